// Round 9
// baseline (280.839 us; speedup 1.0000x reference)
//
#include <hip/hip_runtime.h>

// LTC cell fused kernel. B=512, S=256, N=256, 6 unfolds.
// R9: TLP restructure. R8 proved the ~22us stall is NOT bandwidth (halved
// traffic, stall unchanged) -> it's barrier-lockstep with 1 block/CU and only
// 4 waves/SIMD. Changes:
//  - grid=512, ONE batch row per block (j=tid>>2, c=tid&3): 2 independent
//    blocks/CU = 8 waves/SIMD; one block's barrier drain hides under the
//    other block's issue.
//  - cross-chunk reduction via 2x __shfl_xor inside the wave (chunks c=0..3
//    are lanes 0..3 of each 4-lane group) - kills the 16KB red[] LDS
//    round-trip and the c==0 serial finalize.
//  - double-buffered v_lds[2][256]: ONE __syncthreads per step (was 2).
//  - fp16 tables as R8 (HQ half2{a,a*mu} dwordx4/quad, WQ half{w*erev}
//    dwordx2/quad), R4-style loop + #pragma unroll 2 + distance-1 rotation
//    (the only shape proven spill-free; R5/R6 straight-line bodies spilled).

#define LOG2E 1.4426950408889634f
#define EXP2_RAW(x) __builtin_amdgcn_exp2f(x)
#define RCP_RAW(x) __builtin_amdgcn_rcpf(x)

typedef float f2 __attribute__((ext_vector_type(2)));
typedef _Float16 h2 __attribute__((ext_vector_type(2)));

constexpr int Bb = 512;
constexpr int Ss = 256;
constexpr int Nn = 256;
constexpr int UNFOLDS = 6;
constexpr float EPS = 1e-8f;
constexpr int PLANE = 16384;  // (Nn/4)*Nn quad entries

struct alignas(16) HQ { h2 a[4]; };        // per i in quad: {a, a*mu}
struct alignas(8)  WQ { _Float16 w[4]; };  // per i in quad: w*erev

__global__ __launch_bounds__(256) void pack_kernel(
    const float* __restrict__ sg, const float* __restrict__ mu,
    const float* __restrict__ w, const float* __restrict__ er,
    const float* __restrict__ ssg, const float* __restrict__ smu,
    const float* __restrict__ sw, const float* __restrict__ ser,
    HQ* __restrict__ pH, WQ* __restrict__ pW,
    HQ* __restrict__ sH, WQ* __restrict__ sW) {
  int idx = blockIdx.x * 256 + threadIdx.x;   // iq*256 + j
  int b = (idx >> 8) * 1024 + (idx & 255);    // row 4*iq, col j
  HQ hq; WQ wq;
#pragma unroll
  for (int k = 0; k < 4; ++k) {
    int o = b + k * 256;
    float a = sg[o] * LOG2E;
    hq.a[k] = h2{(_Float16)a, (_Float16)(a * mu[o])};
    wq.w[k] = (_Float16)(w[o] * er[o]);
  }
  pH[idx] = hq; pW[idx] = wq;
#pragma unroll
  for (int k = 0; k < 4; ++k) {
    int o = b + k * 256;
    float a = ssg[o] * LOG2E;
    hq.a[k] = h2{(_Float16)a, (_Float16)(a * smu[o])};
    wq.w[k] = (_Float16)(sw[o] * ser[o]);
  }
  sH[idx] = hq; sW[idx] = wq;
}

// One contraction pass: 64 i-values (chunk c) x 1 row. Returns {num, den}
// partial sums. R4 loop shape: 16 quads, unroll 2, distance-1 rotation.
template <bool PACKED>
__device__ __forceinline__ f2 pass_accum(
    const HQ* __restrict__ pH, const WQ* __restrict__ pW,
    const float* __restrict__ rS, const float* __restrict__ rM,
    const float* __restrict__ rW, const float* __restrict__ rE,
    const float* __restrict__ xp, int c, int j) {
  f2 na01 = 0.f, na23 = 0.f, da01 = 0.f, da23 = 0.f;
  const int q0 = (c << 4) * 256 + j;  // plane idx of chunk's quad 0
  HQ H; WQ W;
  if constexpr (PACKED) { H = pH[q0]; W = pW[q0]; }
#pragma unroll 2
  for (int ip = 0; ip < 16; ++ip) {
    HQ Hn; WQ Wn;
    f2 a01, a23, m01, m23, wn01, wn23;
    if constexpr (PACKED) {
      const int ni = q0 + ((((ip + 1) & 15)) << 8);  // next quad (wraps)
      Hn = pH[ni]; Wn = pW[ni];
      a01 = f2{(float)H.a[0].x, (float)H.a[1].x};
      a23 = f2{(float)H.a[2].x, (float)H.a[3].x};
      m01 = f2{(float)H.a[0].y, (float)H.a[1].y};
      m23 = f2{(float)H.a[2].y, (float)H.a[3].y};
      wn01 = f2{(float)W.w[0], (float)W.w[1]};
      wn23 = f2{(float)W.w[2], (float)W.w[3]};
    } else {
      const int b = (c * 64 + ip * 4) * Nn + j;
      a01 = f2{rS[b] * LOG2E, rS[b + 256] * LOG2E};
      a23 = f2{rS[b + 512] * LOG2E, rS[b + 768] * LOG2E};
      m01 = f2{a01.x * rM[b], a01.y * rM[b + 256]};
      m23 = f2{a23.x * rM[b + 512], a23.y * rM[b + 768]};
      wn01 = f2{rW[b] * rE[b], rW[b + 256] * rE[b + 256]};
      wn23 = f2{rW[b + 512] * rE[b + 512], rW[b + 768] * rE[b + 768]};
    }
    const f2 wd01 = {__builtin_fabsf(wn01.x), __builtin_fabsf(wn01.y)};
    const f2 wd23 = {__builtin_fabsf(wn23.x), __builtin_fabsf(wn23.y)};
    const float4 xq = *reinterpret_cast<const float4*>(&xp[c * 64 + ip * 4]);
    const f2 x01 = {xq.x, xq.y}, x23 = {xq.z, xq.w};
    const f2 y01 = m01 - a01 * x01;
    const f2 y23 = m23 - a23 * x23;
    f2 s01, s23;
    s01.x = RCP_RAW(1.f + EXP2_RAW(y01.x));
    s01.y = RCP_RAW(1.f + EXP2_RAW(y01.y));
    s23.x = RCP_RAW(1.f + EXP2_RAW(y23.x));
    s23.y = RCP_RAW(1.f + EXP2_RAW(y23.y));
    na01 += wn01 * s01; na23 += wn23 * s23;
    da01 += wd01 * s01; da23 += wd23 * s23;
    if constexpr (PACKED) { H = Hn; W = Wn; }
  }
  return f2{na01.x + na01.y + na23.x + na23.y,
            da01.x + da01.y + da23.x + da23.y};
}

template <bool PACKED>
__global__ __launch_bounds__(1024, 8) void ltc_kernel(
    const float* __restrict__ input, const float* __restrict__ hx,
    const float* __restrict__ ts, const float* __restrict__ gleak,
    const float* __restrict__ vleak, const float* __restrict__ cm,
    const float* __restrict__ input_w, const float* __restrict__ input_b,
    const HQ* __restrict__ pH, const WQ* __restrict__ pW,
    const HQ* __restrict__ sH, const WQ* __restrict__ sW,
    const float* __restrict__ sigmaP, const float* __restrict__ muP,
    const float* __restrict__ wP, const float* __restrict__ erevP,
    const float* __restrict__ ssigmaP, const float* __restrict__ smuP,
    const float* __restrict__ swP, const float* __restrict__ serevP,
    float* __restrict__ out) {
  __shared__ alignas(16) float v_lds[2][Nn];   // double-buffered state
  __shared__ alignas(16) float inp_lds[Ss];

  const int tid = threadIdx.x;
  const int j = tid >> 2;   // output column 0..255
  const int c = tid & 3;    // i-chunk 0..3 (lanes 0..3 of each 4-lane group)
  const int b0 = blockIdx.x;  // one batch row per block

  if (tid < 256) {
    inp_lds[tid] = input[b0 * Ss + tid] * input_w[tid] + input_b[tid];
    v_lds[0][tid] = hx[b0 * Nn + tid];
  }

  // Per-column constants (4 lanes share j -> broadcast loads).
  float vreg = hx[b0 * Nn + j];
  const float glj = gleak[j];
  const float glvl = glj * vleak[j];
  const float cmt = cm[j] / ((ts[b0] + 1.f) / (float)UNFOLDS);

  __syncthreads();

  // ---- sensory pass: partials + intra-wave butterfly over c ----
  float snum, sden;
  {
    f2 s = pass_accum<PACKED>(sH, sW, ssigmaP, smuP, swP, serevP,
                              &inp_lds[0], c, j);
    snum = s.x; sden = s.y;
    snum += __shfl_xor(snum, 1); snum += __shfl_xor(snum, 2);
    sden += __shfl_xor(sden, 1); sden += __shfl_xor(sden, 2);
  }

  // ---- 6 ODE unfolds, one barrier per step ----
  int cur = 0;
  float vo = vreg;
  for (int step = 0; step < UNFOLDS; ++step) {
    f2 a = pass_accum<PACKED>(pH, pW, sigmaP, muP, wP, erevP,
                              &v_lds[cur][0], c, j);
    float num = a.x, den = a.y;
    num += __shfl_xor(num, 1); num += __shfl_xor(num, 2);
    den += __shfl_xor(den, 1); den += __shfl_xor(den, 2);
    num += snum; den += sden;
    vo = (cmt * vreg + glvl + num) / (cmt + glj + den + EPS);
    if (c == 0) v_lds[cur ^ 1][j] = vo;  // write buffer nobody is reading
    vreg = vo;
    cur ^= 1;
    __syncthreads();  // v_next visible; also closes reads of old buffer
  }

  if (c == 0) out[b0 * Nn + j] = vo;
}

extern "C" void kernel_launch(void* const* d_in, const int* in_sizes, int n_in,
                              void* d_out, int out_size, void* d_ws, size_t ws_size,
                              hipStream_t stream) {
  const float* input   = (const float*)d_in[0];
  const float* hx      = (const float*)d_in[1];
  const float* ts      = (const float*)d_in[2];
  const float* gleak   = (const float*)d_in[3];
  const float* vleak   = (const float*)d_in[4];
  const float* cm      = (const float*)d_in[5];
  const float* sigma   = (const float*)d_in[6];
  const float* mu      = (const float*)d_in[7];
  const float* w       = (const float*)d_in[8];
  const float* erev    = (const float*)d_in[9];
  const float* ssigma  = (const float*)d_in[10];
  const float* smu     = (const float*)d_in[11];
  const float* sw      = (const float*)d_in[12];
  const float* serev   = (const float*)d_in[13];
  const float* input_w = (const float*)d_in[14];
  const float* input_b = (const float*)d_in[15];
  float* out = (float*)d_out;

  // pH 256KB | sH 256KB | pW 128KB | sW 128KB = 768KB
  const size_t need = (size_t)PLANE * (sizeof(HQ) * 2 + sizeof(WQ) * 2);
  if (ws_size >= need) {
    HQ* pH = (HQ*)d_ws;
    HQ* sH = pH + PLANE;
    WQ* pW = (WQ*)(sH + PLANE);
    WQ* sW = pW + PLANE;
    pack_kernel<<<PLANE / 256, 256, 0, stream>>>(sigma, mu, w, erev, ssigma,
                                                 smu, sw, serev, pH, pW, sH, sW);
    ltc_kernel<true><<<Bb, 1024, 0, stream>>>(
        input, hx, ts, gleak, vleak, cm, input_w, input_b, pH, pW, sH, sW,
        sigma, mu, w, erev, ssigma, smu, sw, serev, out);
  } else {
    ltc_kernel<false><<<Bb, 1024, 0, stream>>>(
        input, hx, ts, gleak, vleak, cm, input_w, input_b,
        nullptr, nullptr, nullptr, nullptr,
        sigma, mu, w, erev, ssigma, smu, sw, serev, out);
  }
}

// Round 10
// 168.115 us; speedup vs baseline: 1.6705x; 1.6705x over previous
//
#include <hip/hip_runtime.h>

// LTC cell fused kernel. B=512, S=256, N=256, 6 unfolds.
// R10: the TLP experiment R9 botched, with R8's proven memory layout intact.
//  - R9 lesson (pinned): param coalescing REQUIRES j=tid&255 (wave lanes =
//    consecutive j) and wave-uniform c. R9's j=tid>>2 scattered every wave's
//    param loads (16 segments vs 1) and 4-way-aliased the LDS x-reads ->
//    211us at 92% occupancy. Layout here is bit-identical to R8.
//  - Change vs R8: ONE batch row per block, grid=512, __launch_bounds__(1024,8)
//    -> 2 independent 1024-thread blocks per CU (2048 thr/CU). One block's
//    barrier drain hides under the other block's issue stream.
//  - fp16 tables as R8 (HQ half2{a,a*mu} dwordx4/quad, WQ half{w*erev}
//    dwordx2/quad), R4/R8 loop shape: 16 quads, #pragma unroll 2, distance-1
//    rotation (only shape proven spill-free).

#define LOG2E 1.4426950408889634f
#define EXP2_RAW(x) __builtin_amdgcn_exp2f(x)
#define RCP_RAW(x) __builtin_amdgcn_rcpf(x)

typedef float f2 __attribute__((ext_vector_type(2)));
typedef _Float16 h2 __attribute__((ext_vector_type(2)));

constexpr int Bb = 512;
constexpr int Ss = 256;
constexpr int Nn = 256;
constexpr int UNFOLDS = 6;
constexpr float EPS = 1e-8f;
constexpr int PLANE = 16384;  // (Nn/4)*Nn quad entries

struct alignas(16) HQ { h2 a[4]; };        // per i in quad: {a, a*mu}
struct alignas(8)  WQ { _Float16 w[4]; };  // per i in quad: w*erev

__global__ __launch_bounds__(256) void pack_kernel(
    const float* __restrict__ sg, const float* __restrict__ mu,
    const float* __restrict__ w, const float* __restrict__ er,
    const float* __restrict__ ssg, const float* __restrict__ smu,
    const float* __restrict__ sw, const float* __restrict__ ser,
    HQ* __restrict__ pH, WQ* __restrict__ pW,
    HQ* __restrict__ sH, WQ* __restrict__ sW) {
  int idx = blockIdx.x * 256 + threadIdx.x;   // iq*256 + j
  int b = (idx >> 8) * 1024 + (idx & 255);    // row 4*iq, col j
  HQ hq; WQ wq;
#pragma unroll
  for (int k = 0; k < 4; ++k) {
    int o = b + k * 256;
    float a = sg[o] * LOG2E;
    hq.a[k] = h2{(_Float16)a, (_Float16)(a * mu[o])};
    wq.w[k] = (_Float16)(w[o] * er[o]);
  }
  pH[idx] = hq; pW[idx] = wq;
#pragma unroll
  for (int k = 0; k < 4; ++k) {
    int o = b + k * 256;
    float a = ssg[o] * LOG2E;
    hq.a[k] = h2{(_Float16)a, (_Float16)(a * smu[o])};
    wq.w[k] = (_Float16)(sw[o] * ser[o]);
  }
  sH[idx] = hq; sW[idx] = wq;
}

// One contraction pass: 64 i-values (chunk c) x 1 row for column j.
// R8 loop shape: 16 quads, unroll 2, distance-1 rotation. Returns {num,den}.
template <bool PACKED>
__device__ __forceinline__ f2 pass_accum(
    const HQ* __restrict__ pH, const WQ* __restrict__ pW,
    const float* __restrict__ rS, const float* __restrict__ rM,
    const float* __restrict__ rW, const float* __restrict__ rE,
    const float* __restrict__ xp, int c, int j) {
  f2 na01 = 0.f, na23 = 0.f, da01 = 0.f, da23 = 0.f;
  const int q0 = c * 4096 + j;  // plane idx of chunk's quad 0 (same as R8)
  HQ H; WQ W;
  if constexpr (PACKED) { H = pH[q0]; W = pW[q0]; }
#pragma unroll 2
  for (int ip = 0; ip < 16; ++ip) {
    HQ Hn; WQ Wn;
    f2 a01, a23, m01, m23, wn01, wn23;
    if constexpr (PACKED) {
      const int ni = q0 + (((ip + 1) & 15) << 8);  // next quad (wraps)
      Hn = pH[ni]; Wn = pW[ni];
      a01 = f2{(float)H.a[0].x, (float)H.a[1].x};
      a23 = f2{(float)H.a[2].x, (float)H.a[3].x};
      m01 = f2{(float)H.a[0].y, (float)H.a[1].y};
      m23 = f2{(float)H.a[2].y, (float)H.a[3].y};
      wn01 = f2{(float)W.w[0], (float)W.w[1]};
      wn23 = f2{(float)W.w[2], (float)W.w[3]};
    } else {
      const int b = (c * 64 + ip * 4) * Nn + j;
      a01 = f2{rS[b] * LOG2E, rS[b + 256] * LOG2E};
      a23 = f2{rS[b + 512] * LOG2E, rS[b + 768] * LOG2E};
      m01 = f2{a01.x * rM[b], a01.y * rM[b + 256]};
      m23 = f2{a23.x * rM[b + 512], a23.y * rM[b + 768]};
      wn01 = f2{rW[b] * rE[b], rW[b + 256] * rE[b + 256]};
      wn23 = f2{rW[b + 512] * rE[b + 512], rW[b + 768] * rE[b + 768]};
    }
    const f2 wd01 = {__builtin_fabsf(wn01.x), __builtin_fabsf(wn01.y)};
    const f2 wd23 = {__builtin_fabsf(wn23.x), __builtin_fabsf(wn23.y)};
    // x-read: address is wave-uniform (c, ip) -> LDS broadcast, no conflict.
    const float4 xq = *reinterpret_cast<const float4*>(&xp[c * 64 + ip * 4]);
    const f2 x01 = {xq.x, xq.y}, x23 = {xq.z, xq.w};
    const f2 y01 = m01 - a01 * x01;
    const f2 y23 = m23 - a23 * x23;
    f2 s01, s23;
    s01.x = RCP_RAW(1.f + EXP2_RAW(y01.x));
    s01.y = RCP_RAW(1.f + EXP2_RAW(y01.y));
    s23.x = RCP_RAW(1.f + EXP2_RAW(y23.x));
    s23.y = RCP_RAW(1.f + EXP2_RAW(y23.y));
    na01 += wn01 * s01; na23 += wn23 * s23;
    da01 += wd01 * s01; da23 += wd23 * s23;
    if constexpr (PACKED) { H = Hn; W = Wn; }
  }
  return f2{na01.x + na01.y + na23.x + na23.y,
            da01.x + da01.y + da23.x + da23.y};
}

template <bool PACKED>
__global__ __launch_bounds__(1024, 8) void ltc_kernel(
    const float* __restrict__ input, const float* __restrict__ hx,
    const float* __restrict__ ts, const float* __restrict__ gleak,
    const float* __restrict__ vleak, const float* __restrict__ cm,
    const float* __restrict__ input_w, const float* __restrict__ input_b,
    const HQ* __restrict__ pH, const WQ* __restrict__ pW,
    const HQ* __restrict__ sH, const WQ* __restrict__ sW,
    const float* __restrict__ sigmaP, const float* __restrict__ muP,
    const float* __restrict__ wP, const float* __restrict__ erevP,
    const float* __restrict__ ssigmaP, const float* __restrict__ smuP,
    const float* __restrict__ swP, const float* __restrict__ serevP,
    float* __restrict__ out) {
  __shared__ alignas(16) float v_lds[2][Nn];   // double-buffered state
  __shared__ alignas(16) float inp_lds[Ss];
  __shared__ alignas(16) f2 red[1024];         // 8 KB partials

  const int tid = threadIdx.x;
  const int j = tid & 255;    // column: wave lanes = consecutive j (coalesce!)
  const int c = tid >> 8;     // i-chunk 0..3, wave-uniform
  const int b0 = blockIdx.x;  // one batch row per block

  if (tid < 256) {
    inp_lds[tid] = input[b0 * Ss + tid] * input_w[tid] + input_b[tid];
    v_lds[0][tid] = hx[b0 * Nn + tid];
  }

  const float glj = gleak[j];
  const float glvl = glj * vleak[j];
  const float cmt = cm[j] / ((ts[b0] + 1.f) / (float)UNFOLDS);

  __syncthreads();

  // ---- sensory pass ----
  {
    f2 s = pass_accum<PACKED>(sH, sW, ssigmaP, smuP, swP, serevP,
                              &inp_lds[0], c, j);
    red[tid] = s;
  }
  __syncthreads();
  float snum = 0.f, sden = 0.f;
  if (c == 0) {
    f2 a = red[j], b = red[256 + j], cc = red[512 + j], d = red[768 + j];
    snum = a.x + b.x + cc.x + d.x;
    sden = a.y + b.y + cc.y + d.y;
  }
  __syncthreads();  // red[] reused by step loop

  // ---- 6 ODE unfolds ----
  int cur = 0;
  for (int step = 0; step < UNFOLDS; ++step) {
    f2 a = pass_accum<PACKED>(pH, pW, sigmaP, muP, wP, erevP,
                              &v_lds[cur][0], c, j);
    red[tid] = a;
    __syncthreads();
    if (c == 0) {
      f2 p0 = red[j], p1 = red[256 + j], p2 = red[512 + j], p3 = red[768 + j];
      float num = p0.x + p1.x + p2.x + p3.x + snum;
      float den = p0.y + p1.y + p2.y + p3.y + sden;
      float vp = v_lds[cur][j];
      v_lds[cur ^ 1][j] = (cmt * vp + glvl + num) / (cmt + glj + den + EPS);
    }
    cur ^= 1;
    __syncthreads();
  }

  if (c == 0) out[b0 * Nn + j] = v_lds[cur][j];
}

extern "C" void kernel_launch(void* const* d_in, const int* in_sizes, int n_in,
                              void* d_out, int out_size, void* d_ws, size_t ws_size,
                              hipStream_t stream) {
  const float* input   = (const float*)d_in[0];
  const float* hx      = (const float*)d_in[1];
  const float* ts      = (const float*)d_in[2];
  const float* gleak   = (const float*)d_in[3];
  const float* vleak   = (const float*)d_in[4];
  const float* cm      = (const float*)d_in[5];
  const float* sigma   = (const float*)d_in[6];
  const float* mu      = (const float*)d_in[7];
  const float* w       = (const float*)d_in[8];
  const float* erev    = (const float*)d_in[9];
  const float* ssigma  = (const float*)d_in[10];
  const float* smu     = (const float*)d_in[11];
  const float* sw      = (const float*)d_in[12];
  const float* serev   = (const float*)d_in[13];
  const float* input_w = (const float*)d_in[14];
  const float* input_b = (const float*)d_in[15];
  float* out = (float*)d_out;

  // pH 256KB | sH 256KB | pW 128KB | sW 128KB = 768KB
  const size_t need = (size_t)PLANE * (sizeof(HQ) * 2 + sizeof(WQ) * 2);
  if (ws_size >= need) {
    HQ* pH = (HQ*)d_ws;
    HQ* sH = pH + PLANE;
    WQ* pW = (WQ*)(sH + PLANE);
    WQ* sW = pW + PLANE;
    pack_kernel<<<PLANE / 256, 256, 0, stream>>>(sigma, mu, w, erev, ssigma,
                                                 smu, sw, serev, pH, pW, sH, sW);
    ltc_kernel<true><<<Bb, 1024, 0, stream>>>(
        input, hx, ts, gleak, vleak, cm, input_w, input_b, pH, pW, sH, sW,
        sigma, mu, w, erev, ssigma, smu, sw, serev, out);
  } else {
    ltc_kernel<false><<<Bb, 1024, 0, stream>>>(
        input, hx, ts, gleak, vleak, cm, input_w, input_b,
        nullptr, nullptr, nullptr, nullptr,
        sigma, mu, w, erev, ssigma, smu, sw, serev, out);
  }
}